// Round 7
// baseline (7855.407 us; speedup 1.0000x reference)
//
#include <hip/hip_runtime.h>
#include <math.h>

#define B_N 32
#define T_N 1024
#define E_N 512
#define H_N 512
#define G4_N 2048  // 4*H

typedef __attribute__((ext_vector_type(8))) short short8;
typedef __attribute__((ext_vector_type(4))) float f32x4;
typedef __attribute__((ext_vector_type(4))) unsigned int uint32x4;
typedef unsigned long long ull;

__device__ __forceinline__ unsigned short f2bfu(float f) {
  unsigned int x = __builtin_bit_cast(unsigned int, f);
  x += 0x7fffu + ((x >> 16) & 1u);
  return (unsigned short)(x >> 16);
}
__device__ __forceinline__ float bfu2f(unsigned short u) {
  return __builtin_bit_cast(float, ((unsigned int)u) << 16);
}
__device__ __forceinline__ float sigmf(float x) { return 1.0f / (1.0f + expf(-x)); }

// ---- agent-scope (MALL-coherent, L1+L2 bypass) access helpers -------------
__device__ __forceinline__ void load64_mall(const unsigned short* p,
                                            uint32x4& a, uint32x4& b,
                                            uint32x4& c, uint32x4& d) {
  asm volatile("global_load_dwordx4 %0, %4, off sc0 sc1\n\t"
               "global_load_dwordx4 %1, %4, off offset:16 sc0 sc1\n\t"
               "global_load_dwordx4 %2, %4, off offset:32 sc0 sc1\n\t"
               "global_load_dwordx4 %3, %4, off offset:48 sc0 sc1\n\t"
               "s_waitcnt vmcnt(0)"
               : "=&v"(a), "=&v"(b), "=&v"(c), "=&v"(d)
               : "v"(p) : "memory");
}
__device__ __forceinline__ void load64_mall_nowait(const unsigned short* p,
                                                   uint32x4& a, uint32x4& b,
                                                   uint32x4& c, uint32x4& d) {
  asm volatile("global_load_dwordx4 %0, %4, off sc0 sc1\n\t"
               "global_load_dwordx4 %1, %4, off offset:16 sc0 sc1\n\t"
               "global_load_dwordx4 %2, %4, off offset:32 sc0 sc1\n\t"
               "global_load_dwordx4 %3, %4, off offset:48 sc0 sc1"
               : "=&v"(a), "=&v"(b), "=&v"(c), "=&v"(d)
               : "v"(p) : "memory");
}
__device__ __forceinline__ void store32_mall(unsigned int* p, unsigned int v) {
  asm volatile("global_store_dword %0, %1, off sc0 sc1" :: "v"(p), "v"(v) : "memory");
}

// ---------------------------------------------------------------------------
// Kernel 1 (unchanged): xw[dir][t_local][g][b] bf16 = W_ih[dir] @ x(+rev) + b
// ---------------------------------------------------------------------------
__global__ __launch_bounds__(256) void xw_gemm_kernel(
    const float* __restrict__ xs, const int* __restrict__ lengths,
    const float* __restrict__ w_ih_f, const float* __restrict__ b_f,
    const float* __restrict__ w_ih_b, const float* __restrict__ b_b,
    unsigned short* __restrict__ xw, int t0, int Tseg)
{
  __shared__ unsigned short As[64][80];
  __shared__ unsigned short Bs[64][80];
  const int g0 = blockIdx.x * 64;
  const int n0 = blockIdx.y * 64;
  const int dir = blockIdx.z;
  const float* __restrict__ W = dir ? w_ih_b : w_ih_f;
  const float* __restrict__ bias = dir ? b_b : b_f;
  const int tid = threadIdx.x;
  const int w = tid >> 6, lane = tid & 63;
  const int wr = w >> 1, wc = w & 1;

  const int sr = tid >> 2;
  const int sq = tid & 3;
  const int nrow = n0 + sr;
  const int bb = nrow & 31;
  const int tt = t0 + (nrow >> 5);
  const int Lb = lengths[bb];
  const int src_t = (dir != 0 && tt < Lb) ? (Lb - 1 - tt) : tt;
  const float* __restrict__ xrow = xs + ((size_t)bb * T_N + src_t) * E_N;
  const float* __restrict__ arow = W + (size_t)(g0 + sr) * E_N;

  f32x4 acc[2][2] = {};

  for (int k0 = 0; k0 < E_N; k0 += 64) {
    float4 av[4], bv[4];
#pragma unroll
    for (int i = 0; i < 4; ++i) {
      av[i] = *(const float4*)&arow[k0 + sq * 16 + i * 4];
      bv[i] = *(const float4*)&xrow[k0 + sq * 16 + i * 4];
    }
    __syncthreads();
#pragma unroll
    for (int i = 0; i < 4; ++i) {
      ushort4 a4, b4;
      a4.x = f2bfu(av[i].x); a4.y = f2bfu(av[i].y); a4.z = f2bfu(av[i].z); a4.w = f2bfu(av[i].w);
      b4.x = f2bfu(bv[i].x); b4.y = f2bfu(bv[i].y); b4.z = f2bfu(bv[i].z); b4.w = f2bfu(bv[i].w);
      *(ushort4*)&As[sr][sq * 16 + i * 4] = a4;
      *(ushort4*)&Bs[sr][sq * 16 + i * 4] = b4;
    }
    __syncthreads();
#pragma unroll
    for (int kk = 0; kk < 2; ++kk) {
      const int ko = kk * 32 + ((lane >> 4) << 3);
      short8 bf0 = *(const short8*)&Bs[wc * 32 + (lane & 15)][ko];
      short8 bf1 = *(const short8*)&Bs[wc * 32 + 16 + (lane & 15)][ko];
      short8 af0 = *(const short8*)&As[wr * 32 + (lane & 15)][ko];
      short8 af1 = *(const short8*)&As[wr * 32 + 16 + (lane & 15)][ko];
      acc[0][0] = __builtin_amdgcn_mfma_f32_16x16x32_bf16(af0, bf0, acc[0][0], 0, 0, 0);
      acc[0][1] = __builtin_amdgcn_mfma_f32_16x16x32_bf16(af0, bf1, acc[0][1], 0, 0, 0);
      acc[1][0] = __builtin_amdgcn_mfma_f32_16x16x32_bf16(af1, bf0, acc[1][0], 0, 0, 0);
      acc[1][1] = __builtin_amdgcn_mfma_f32_16x16x32_bf16(af1, bf1, acc[1][1], 0, 0, 0);
    }
  }

#pragma unroll
  for (int mt = 0; mt < 2; ++mt)
#pragma unroll
    for (int nt = 0; nt < 2; ++nt)
#pragma unroll
      for (int j = 0; j < 4; ++j) {
        const int m = g0 + wr * 32 + mt * 16 + ((lane >> 4) << 2) + j;
        const int n = n0 + wc * 32 + nt * 16 + (lane & 15);
        const int tl = n >> 5, b = n & 31;
        const float v = acc[mt][nt][j] + bias[m];
        xw[(((size_t)dir * Tseg + tl) * G4_N + m) * B_N + b] = f2bfu(v);
      }
}

// ---------------------------------------------------------------------------
// Kernel 2: dir-interleaved persistent recurrence, 32 wgs x 512 threads.
// wg cg handles column-group cg of BOTH directions: phase A = dir0 step t,
// phase B = dir1 step t. Per-wave flags flg[dir][cg][wave] (value v = h(v) at
// MALL). Speculative pre-stage: flag of the other dir read at P1, checked
// post-S2 (__all); on hit the 64B slice loads issue immediately (fresh: after
// flag observed) and drain at the publish vmcnt(0) -> next phase stages from
// registers. Fallback = R6 poll+load path (wave-uniform).
// ---------------------------------------------------------------------------
__global__ __launch_bounds__(512, 1) void rec_kernel(
    const unsigned short* __restrict__ xw,
    const float* __restrict__ w_hh_f, const float* __restrict__ w_hh_b,
    const float* __restrict__ w_cls, const int* __restrict__ lengths,
    unsigned short* __restrict__ hx,         // [2][2][32][32][16] bf16
    unsigned int* __restrict__ flg,          // [2][32][8] u32
    float* __restrict__ c_buf,               // [2][B][H]
    float* __restrict__ lpart,               // [64 slot][B][T][2]
    int t0, int Tseg)
{
  __shared__ unsigned short Ah[32][520];   // 33.3 KB
  __shared__ float gate_p[8][32][17];      // 17.4 KB
  __shared__ float lp[2][16][33][2];       // 8.4 KB

  const int tid = threadIdx.x;
  const int cg = blockIdx.x;               // 0..31
  const int colbase = cg * 16;
  const int w = tid >> 6, lane = tid & 63;
  const int q = w >> 1, kh = w & 1;
  const int b = tid >> 4;                  // 32
  const int cl = tid & 15;                 // 16
  const int col = colbase + cl;
  const int Lb = lengths[b];
  const int Lb_r = lengths[tid & 31];

  // one-time: W_hh fragments for BOTH dirs (gate q, K-half kh)
  short8 wfrag[2][8];
#pragma unroll
  for (int d = 0; d < 2; ++d) {
    const float* __restrict__ whh = d ? w_hh_b : w_hh_f;
    const int grow = q * 512 + colbase + (lane & 15);
    const int kb = (lane >> 4) << 3;
    const float* __restrict__ wr_ = &whh[(size_t)grow * H_N + kh * 256];
#pragma unroll
    for (int ks = 0; ks < 8; ++ks) {
      const float4 f0 = *(const float4*)&wr_[ks * 32 + kb];
      const float4 f1 = *(const float4*)&wr_[ks * 32 + kb + 4];
      short8 v;
      v[0] = (short)f2bfu(f0.x); v[1] = (short)f2bfu(f0.y);
      v[2] = (short)f2bfu(f0.z); v[3] = (short)f2bfu(f0.w);
      v[4] = (short)f2bfu(f1.x); v[5] = (short)f2bfu(f1.y);
      v[6] = (short)f2bfu(f1.z); v[7] = (short)f2bfu(f1.w);
      wfrag[d][ks] = v;
    }
  }

  float cc[2], hh[2], wc0[2], wc1[2];
#pragma unroll
  for (int d = 0; d < 2; ++d) {
    cc[d] = c_buf[((size_t)d * B_N + b) * H_N + col];
    hh[d] = bfu2f(hx[((size_t)d * 2 + (t0 & 1)) * 16384 + ((size_t)cg * 32 + b) * 16 + cl]);
    wc0[d] = w_cls[d * H_N + col];
    wc1[d] = w_cls[2 * H_N + d * H_N + col];
  }

  // step-0 xw prefetch, both dirs
  unsigned short xv[2][4];
#pragma unroll
  for (int d = 0; d < 2; ++d) {
    const unsigned short* __restrict__ xb =
        &xw[((size_t)(d * Tseg) * G4_N + colbase + cl) * B_N + b];
#pragma unroll
    for (int q2 = 0; q2 < 4; ++q2) xv[d][q2] = xb[(size_t)q2 * 512 * B_N];
  }

  uint32x4 sp0, sp1, sp2, sp3;             // speculative slice (one dir at a time)
  bool spok[2] = {false, false};

  const int myfw = (tid & 15) >> 1;        // producer-wave index of my slice
  const int b0 = (tid & 15) * 2, cg16 = (tid >> 4) * 16;

  for (int ts = 0; ts < Tseg; ++ts) {
    const int t = t0 + ts;

#pragma unroll
    for (int d = 0; d < 2; ++d) {
      const int e = d ^ 1;
      const int te = t + d;                // step the spec targets for dir e

      // ---- P1: obtain Ah for dir d, step t ----
      if (spok[d]) {
        asm volatile("s_waitcnt vmcnt(0)" ::: "memory");
        __builtin_amdgcn_sched_barrier(0);
        *(uint32x4*)&Ah[b0][cg16] = sp0;
        *(uint32x4*)&Ah[b0][cg16 + 8] = sp1;
        *(uint32x4*)&Ah[b0 + 1][cg16] = sp2;
        *(uint32x4*)&Ah[b0 + 1][cg16 + 8] = sp3;
      } else {
        unsigned int* pf = flg + ((size_t)d * 32 + (tid >> 4)) * 8 + myfw;
        while (__hip_atomic_load(pf, __ATOMIC_RELAXED, __HIP_MEMORY_SCOPE_AGENT) < (unsigned int)t) {}
        uint32x4 va, vb, vc, vd;
        load64_mall(hx + ((size_t)d * 2 + (t & 1)) * 16384 + (size_t)tid * 32, va, vb, vc, vd);
        *(uint32x4*)&Ah[b0][cg16] = va;
        *(uint32x4*)&Ah[b0][cg16 + 8] = vb;
        *(uint32x4*)&Ah[b0 + 1][cg16] = vc;
        *(uint32x4*)&Ah[b0 + 1][cg16 + 8] = vd;
      }
      // early flag read for the other dir (value consumed post-S2)
      unsigned int fve = __hip_atomic_load(
          flg + ((size_t)e * 32 + (tid >> 4)) * 8 + myfw,
          __ATOMIC_RELAXED, __HIP_MEMORY_SCOPE_AGENT);

      __syncthreads();  // S1: Ah ready

      // ---- P2: previous step's logits reduce (dir d) + xw prefetch ----
      if (ts > 0 && tid < 64) {
        const int br = tid & 31, tau = tid >> 5;
        const int tp = t - 1;
        if (tp < Lb_r) {
          float s = 0.f;
#pragma unroll
          for (int k = 0; k < 16; ++k) s += lp[d][k][br][tau];
          const int tpos = d ? (Lb_r - 1 - tp) : tp;
          lpart[((size_t)(cg * 2 + d) * B_N + br) * T_N * 2 + (size_t)tpos * 2 + tau] = s;
        }
      }
      unsigned short xvn[4];
      if (ts + 1 < Tseg) {
        const unsigned short* __restrict__ xb =
            &xw[((size_t)(d * Tseg + ts + 1) * G4_N + colbase + cl) * B_N + b];
#pragma unroll
        for (int q2 = 0; q2 < 4; ++q2) xvn[q2] = xb[(size_t)q2 * 512 * B_N];
      }

      // ---- P3: MFMA (wave w: gate q, K-half kh) ----
      {
        f32x4 acc0 = {0.f, 0.f, 0.f, 0.f}, acc1 = {0.f, 0.f, 0.f, 0.f};
        const int kb = (lane >> 4) << 3;
#pragma unroll
        for (int ks = 0; ks < 8; ++ks) {
          const int kk = kh * 256 + (ks << 5) + kb;
          short8 a0 = *(const short8*)&Ah[(lane & 15)][kk];
          short8 a1 = *(const short8*)&Ah[16 + (lane & 15)][kk];
          acc0 = __builtin_amdgcn_mfma_f32_16x16x32_bf16(a0, wfrag[d][ks], acc0, 0, 0, 0);
          acc1 = __builtin_amdgcn_mfma_f32_16x16x32_bf16(a1, wfrag[d][ks], acc1, 0, 0, 0);
        }
        const int crow = (lane >> 4) << 2;
        const int ccol = lane & 15;
#pragma unroll
        for (int j = 0; j < 4; ++j) {
          gate_p[w][crow + j][ccol] = acc0[j];
          gate_p[w][16 + crow + j][ccol] = acc1[j];
        }
      }
      __syncthreads();  // S2: gate_p ready

      // ---- P4: speculative pre-stage for dir e, step te ----
      {
        const bool in_seg = (d == 0) || (ts + 1 < Tseg);
        const bool ok = in_seg && __all(fve >= (unsigned int)te);
        if (ok) {
          load64_mall_nowait(hx + ((size_t)e * 2 + (te & 1)) * 16384 + (size_t)tid * 32,
                             sp0, sp1, sp2, sp3);
        }
        spok[e] = ok;
      }

      // ---- P5: epilogue (fp32) ----
      const bool valid = (t < Lb);
      float hn;
      {
        const float gi = gate_p[0][b][cl] + gate_p[1][b][cl] + bfu2f(xv[d][0]);
        const float gf = gate_p[2][b][cl] + gate_p[3][b][cl] + bfu2f(xv[d][1]);
        const float gg = gate_p[4][b][cl] + gate_p[5][b][cl] + bfu2f(xv[d][2]);
        const float go = gate_p[6][b][cl] + gate_p[7][b][cl] + bfu2f(xv[d][3]);
        const float cn = sigmf(gf) * cc[d] + sigmf(gi) * tanhf(gg);
        hn = sigmf(go) * tanhf(cn);
        if (valid) { cc[d] = cn; hh[d] = hn; }
      }
      lp[d][cl][b][0] = valid ? hn * wc0[d] : 0.f;
      lp[d][cl][b][1] = valid ? hn * wc1[d] : 0.f;
#pragma unroll
      for (int q2 = 0; q2 < 4; ++q2) xv[d][q2] = xvn[q2];

      // ---- P6: publish h pair (MALL) ----
      {
        const float hhp = __shfl_xor(hh[d], 1);
        if ((cl & 1) == 0) {
          const unsigned int pv =
              (unsigned int)f2bfu(hh[d]) | ((unsigned int)f2bfu(hhp) << 16);
          store32_mall((unsigned int*)(hx + ((size_t)d * 2 + ((t + 1) & 1)) * 16384 +
                                       ((size_t)cg * 32 + b) * 16 + cl),
                       pv);
        }
      }

      // ---- P7: per-wave drain + flag ----
      asm volatile("s_waitcnt vmcnt(0)" ::: "memory");
      __builtin_amdgcn_sched_barrier(0);
      if (lane == 0)
        store32_mall(flg + ((size_t)d * 32 + cg) * 8 + w, (unsigned int)(t + 1));
    }
  }

  // final step's logits reduce + persist c
#pragma unroll
  for (int d = 0; d < 2; ++d) {
    if (tid < 64) {
      const int br = tid & 31, tau = tid >> 5;
      const int tp = t0 + Tseg - 1;
      if (tp < Lb_r) {
        float s = 0.f;
#pragma unroll
        for (int k = 0; k < 16; ++k) s += lp[d][k][br][tau];
        const int tpos = d ? (Lb_r - 1 - tp) : tp;
        lpart[((size_t)(cg * 2 + d) * B_N + br) * T_N * 2 + (size_t)tpos * 2 + tau] = s;
      }
    }
    c_buf[((size_t)d * B_N + b) * H_N + col] = cc[d];
  }
}

// ---------------------------------------------------------------------------
__global__ void init_kernel(ull* __restrict__ hx64, float* __restrict__ c_buf,
                            unsigned int* __restrict__ flg)
{
  const int i = blockIdx.x * 256 + threadIdx.x;  // 0..65535
  if (i < 16384) hx64[i] = 0ull;                 // hx: 128 KB of zeros
  if (i < 2 * B_N * H_N) c_buf[i] = 0.f;
  if (i < 512) flg[i] = 0u;
}

__global__ void reduce_softmax_kernel(const float* __restrict__ lpart,
                                      const float* __restrict__ b_cls,
                                      float* __restrict__ out)
{
  const int i = blockIdx.x * 256 + threadIdx.x;  // 0..32767
  if (i >= B_N * T_N) return;
  float s0 = b_cls[0], s1 = b_cls[1];
  const float* __restrict__ p = lpart + (size_t)i * 2;
#pragma unroll 8
  for (int wg = 0; wg < 64; ++wg) {
    s0 += p[(size_t)wg * B_N * T_N * 2];
    s1 += p[(size_t)wg * B_N * T_N * 2 + 1];
  }
  const float m = fmaxf(s0, s1);
  const float e0 = expf(s0 - m), e1 = expf(s1 - m);
  const float inv = 1.f / (e0 + e1);
  out[2 * i] = e0 * inv;
  out[2 * i + 1] = e1 * inv;
}

// ---------------------------------------------------------------------------
extern "C" void kernel_launch(void* const* d_in, const int* in_sizes, int n_in,
                              void* d_out, int out_size, void* d_ws, size_t ws_size,
                              hipStream_t stream)
{
  const float* xs      = (const float*)d_in[0];
  const int*   lengths = (const int*)d_in[1];
  const float* w_ih_f  = (const float*)d_in[3];
  const float* w_hh_f  = (const float*)d_in[4];
  const float* b_f     = (const float*)d_in[5];
  const float* w_ih_b  = (const float*)d_in[6];
  const float* w_hh_b  = (const float*)d_in[7];
  const float* b_b     = (const float*)d_in[8];
  const float* w_cls   = (const float*)d_in[9];
  const float* b_cls   = (const float*)d_in[10];
  float* out = (float*)d_out;

  auto alignup = [](size_t v) { return (v + 255) & ~(size_t)255; };
  const size_t hx_b    = alignup((size_t)2 * 2 * 32 * 32 * 16 * 2);   // 128 KB
  const size_t flg_b   = alignup((size_t)512 * 4);                    // 2 KB
  const size_t cbuf_b  = alignup((size_t)2 * B_N * H_N * 4);          // 128 KB
  const size_t lpart_b = alignup((size_t)64 * B_N * T_N * 2 * 4);     // 16 MB
  const size_t fixed = hx_b + flg_b + cbuf_b + lpart_b + 1024;

  int nseg = 1;
  while (nseg < 64) {
    const size_t xwb = alignup((size_t)2 * (T_N / nseg) * G4_N * B_N * 2);
    if (xwb + fixed <= ws_size) break;
    nseg <<= 1;
  }
  const int Tseg = T_N / nseg;
  const size_t xw_b = alignup((size_t)2 * Tseg * G4_N * B_N * 2);

  char* p = (char*)d_ws;
  unsigned short* xw = (unsigned short*)p;  p += xw_b;
  unsigned short* hx = (unsigned short*)p;  p += hx_b;
  unsigned int* flg = (unsigned int*)p;     p += flg_b;
  float* c_buf = (float*)p;                 p += cbuf_b;
  float* lpart = (float*)p;                 p += lpart_b;

  hipMemsetAsync(lpart, 0, lpart_b, stream);
  init_kernel<<<256, 256, 0, stream>>>((ull*)hx, c_buf, flg);

  for (int s = 0; s < nseg; ++s) {
    const int t0 = s * Tseg;
    dim3 g(G4_N / 64, (Tseg * B_N) / 64, 2);
    xw_gemm_kernel<<<g, 256, 0, stream>>>(xs, lengths, w_ih_f, b_f, w_ih_b, b_b, xw, t0, Tseg);
    rec_kernel<<<32, 512, 0, stream>>>(xw, w_hh_f, w_hh_b, w_cls, lengths,
                                       hx, flg, c_buf, lpart, t0, Tseg);
  }

  reduce_softmax_kernel<<<128, 256, 0, stream>>>(lpart, b_cls, out);
}

// Round 8
// 4453.381 us; speedup vs baseline: 1.7639x; 1.7639x over previous
//
#include <hip/hip_runtime.h>
#include <math.h>

#define B_N 32
#define T_N 1024
#define E_N 512
#define H_N 512
#define G4_N 2048  // 4*H

typedef __attribute__((ext_vector_type(8))) short short8;
typedef __attribute__((ext_vector_type(4))) float f32x4;
typedef __attribute__((ext_vector_type(4))) unsigned int uint32x4;
typedef unsigned long long ull;

__device__ __forceinline__ unsigned short f2bfu(float f) {
  unsigned int x = __builtin_bit_cast(unsigned int, f);
  x += 0x7fffu + ((x >> 16) & 1u);
  return (unsigned short)(x >> 16);
}
__device__ __forceinline__ float bfu2f(unsigned short u) {
  return __builtin_bit_cast(float, ((unsigned int)u) << 16);
}
__device__ __forceinline__ float sigmf(float x) { return 1.0f / (1.0f + expf(-x)); }

// ---- agent-scope (MALL-coherent, L1+L2 bypass) access helpers -------------
__device__ __forceinline__ void load64_mall(const unsigned short* p,
                                            uint32x4& a, uint32x4& b,
                                            uint32x4& c, uint32x4& d) {
  asm volatile("global_load_dwordx4 %0, %4, off sc0 sc1\n\t"
               "global_load_dwordx4 %1, %4, off offset:16 sc0 sc1\n\t"
               "global_load_dwordx4 %2, %4, off offset:32 sc0 sc1\n\t"
               "global_load_dwordx4 %3, %4, off offset:48 sc0 sc1\n\t"
               "s_waitcnt vmcnt(0)"
               : "=&v"(a), "=&v"(b), "=&v"(c), "=&v"(d)
               : "v"(p) : "memory");
}
__device__ __forceinline__ void store32_mall(unsigned int* p, unsigned int v) {
  asm volatile("global_store_dword %0, %1, off sc0 sc1" :: "v"(p), "v"(v) : "memory");
}

// Pipelined 2-deep flag poll: two loads in flight, ping-pong checks.
// Poll granularity ~RT/2 instead of RT. On exit, up to ONE flag load is
// still outstanding — the caller's subsequent load64_mall drains it via
// its internal s_waitcnt vmcnt(0) before any data use.
__device__ __forceinline__ void poll_flag2(const unsigned int* pf, unsigned int want) {
  unsigned int fa, fb;
  asm volatile("global_load_dword %0, %2, off sc0 sc1\n\t"
               "global_load_dword %1, %2, off sc0 sc1"
               : "=&v"(fa), "=&v"(fb) : "v"(pf) : "memory");
  for (;;) {
    asm volatile("s_waitcnt vmcnt(1)" ::: "memory");
    __builtin_amdgcn_sched_barrier(0);
    if (fa >= want) break;
    asm volatile("global_load_dword %0, %1, off sc0 sc1" : "=&v"(fa) : "v"(pf) : "memory");
    asm volatile("s_waitcnt vmcnt(1)" ::: "memory");
    __builtin_amdgcn_sched_barrier(0);
    if (fb >= want) break;
    asm volatile("global_load_dword %0, %1, off sc0 sc1" : "=&v"(fb) : "v"(pf) : "memory");
  }
}

// ---------------------------------------------------------------------------
// Kernel 1 (unchanged): xw[dir][t_local][g][b] bf16 = W_ih[dir] @ x(+rev) + b
// ---------------------------------------------------------------------------
__global__ __launch_bounds__(256) void xw_gemm_kernel(
    const float* __restrict__ xs, const int* __restrict__ lengths,
    const float* __restrict__ w_ih_f, const float* __restrict__ b_f,
    const float* __restrict__ w_ih_b, const float* __restrict__ b_b,
    unsigned short* __restrict__ xw, int t0, int Tseg)
{
  __shared__ unsigned short As[64][80];
  __shared__ unsigned short Bs[64][80];
  const int g0 = blockIdx.x * 64;
  const int n0 = blockIdx.y * 64;
  const int dir = blockIdx.z;
  const float* __restrict__ W = dir ? w_ih_b : w_ih_f;
  const float* __restrict__ bias = dir ? b_b : b_f;
  const int tid = threadIdx.x;
  const int w = tid >> 6, lane = tid & 63;
  const int wr = w >> 1, wc = w & 1;

  const int sr = tid >> 2;
  const int sq = tid & 3;
  const int nrow = n0 + sr;
  const int bb = nrow & 31;
  const int tt = t0 + (nrow >> 5);
  const int Lb = lengths[bb];
  const int src_t = (dir != 0 && tt < Lb) ? (Lb - 1 - tt) : tt;
  const float* __restrict__ xrow = xs + ((size_t)bb * T_N + src_t) * E_N;
  const float* __restrict__ arow = W + (size_t)(g0 + sr) * E_N;

  f32x4 acc[2][2] = {};

  for (int k0 = 0; k0 < E_N; k0 += 64) {
    float4 av[4], bv[4];
#pragma unroll
    for (int i = 0; i < 4; ++i) {
      av[i] = *(const float4*)&arow[k0 + sq * 16 + i * 4];
      bv[i] = *(const float4*)&xrow[k0 + sq * 16 + i * 4];
    }
    __syncthreads();
#pragma unroll
    for (int i = 0; i < 4; ++i) {
      ushort4 a4, b4;
      a4.x = f2bfu(av[i].x); a4.y = f2bfu(av[i].y); a4.z = f2bfu(av[i].z); a4.w = f2bfu(av[i].w);
      b4.x = f2bfu(bv[i].x); b4.y = f2bfu(bv[i].y); b4.z = f2bfu(bv[i].z); b4.w = f2bfu(bv[i].w);
      *(ushort4*)&As[sr][sq * 16 + i * 4] = a4;
      *(ushort4*)&Bs[sr][sq * 16 + i * 4] = b4;
    }
    __syncthreads();
#pragma unroll
    for (int kk = 0; kk < 2; ++kk) {
      const int ko = kk * 32 + ((lane >> 4) << 3);
      short8 bf0 = *(const short8*)&Bs[wc * 32 + (lane & 15)][ko];
      short8 bf1 = *(const short8*)&Bs[wc * 32 + 16 + (lane & 15)][ko];
      short8 af0 = *(const short8*)&As[wr * 32 + (lane & 15)][ko];
      short8 af1 = *(const short8*)&As[wr * 32 + 16 + (lane & 15)][ko];
      acc[0][0] = __builtin_amdgcn_mfma_f32_16x16x32_bf16(af0, bf0, acc[0][0], 0, 0, 0);
      acc[0][1] = __builtin_amdgcn_mfma_f32_16x16x32_bf16(af0, bf1, acc[0][1], 0, 0, 0);
      acc[1][0] = __builtin_amdgcn_mfma_f32_16x16x32_bf16(af1, bf0, acc[1][0], 0, 0, 0);
      acc[1][1] = __builtin_amdgcn_mfma_f32_16x16x32_bf16(af1, bf1, acc[1][1], 0, 0, 0);
    }
  }

#pragma unroll
  for (int mt = 0; mt < 2; ++mt)
#pragma unroll
    for (int nt = 0; nt < 2; ++nt)
#pragma unroll
      for (int j = 0; j < 4; ++j) {
        const int m = g0 + wr * 32 + mt * 16 + ((lane >> 4) << 2) + j;
        const int n = n0 + wc * 32 + nt * 16 + (lane & 15);
        const int tl = n >> 5, b = n & 31;
        const float v = acc[mt][nt][j] + bias[m];
        xw[(((size_t)dir * Tseg + tl) * G4_N + m) * B_N + b] = f2bfu(v);
      }
}

// ---------------------------------------------------------------------------
// Kernel 2: persistent recurrence (R6 structure), per-WAVE flags + pipelined
// poll, 2 barriers/step. 64 wgs x 512 threads; dir = wg&1, cg = wg>>1.
//   hx:  [dir][parity][cg=32][b=32][cl=16] bf16 (data, sc0 sc1)
//   flg: [dir][cg][wave=8] u32, monotonic = steps published by that wave.
// Producer wave covers batches 4w..4w+3 (all 16 cols of its cg); consumer
// thread's slice (rows 2i,2i+1 of cg'=tid>>4) is covered by wave i>>1.
// Safety: consumer passes S1 only after observing flags >= t from every
// producer wave => those waves passed step t-1 epilogue => their h(t-1)
// loads are done => overwriting parity slot (t+1)&1 is race-free.
// ---------------------------------------------------------------------------
__global__ __launch_bounds__(512, 1) void rec_kernel(
    const unsigned short* __restrict__ xw,
    const float* __restrict__ w_hh_f, const float* __restrict__ w_hh_b,
    const float* __restrict__ w_cls, const int* __restrict__ lengths,
    unsigned short* __restrict__ hx,         // [2][2][32][32][16] bf16
    unsigned int* __restrict__ flg,          // [2][32][8] u32
    float* __restrict__ c_buf,               // [2][B][H]
    float* __restrict__ lpart,               // [64 wg][B][T][2]
    int t0, int Tseg)
{
  __shared__ unsigned short Ah[32][520];   // 33.3 KB, row stride 1040B
  __shared__ float gate_p[8][32][17];      // K-half partials
  __shared__ float lp[16][33][2];          // logits partials

  const int tid = threadIdx.x;
  const int wg = blockIdx.x;
  const int dir = wg & 1;
  const int cg = wg >> 1;
  const int colbase = cg * 16;
  const float* __restrict__ w_hh = dir ? w_hh_b : w_hh_f;
  const int w = tid >> 6, lane = tid & 63;
  const int q = w >> 1, kh = w & 1;

  // one-time: W_hh fragments (gate q, K-half kh) into registers
  short8 wfrag[8];
  {
    const int grow = q * 512 + colbase + (lane & 15);
    const int kb = (lane >> 4) << 3;
    const float* __restrict__ wr_ = &w_hh[(size_t)grow * H_N + kh * 256];
#pragma unroll
    for (int ks = 0; ks < 8; ++ks) {
      const float4 f0 = *(const float4*)&wr_[ks * 32 + kb];
      const float4 f1 = *(const float4*)&wr_[ks * 32 + kb + 4];
      short8 v;
      v[0] = (short)f2bfu(f0.x); v[1] = (short)f2bfu(f0.y);
      v[2] = (short)f2bfu(f0.z); v[3] = (short)f2bfu(f0.w);
      v[4] = (short)f2bfu(f1.x); v[5] = (short)f2bfu(f1.y);
      v[6] = (short)f2bfu(f1.z); v[7] = (short)f2bfu(f1.w);
      wfrag[ks] = v;
    }
  }

  // per-thread epilogue ownership: b = tid>>4 (32), cl = tid&15 (16 cols)
  const int b = tid >> 4;
  const int cl = tid & 15;
  const int col = colbase + cl;
  const int Lb = lengths[b];
  const int Lb_r = lengths[tid & 31];      // for the tid<64 logits reducer
  float cc = c_buf[((size_t)dir * B_N + b) * H_N + col];
  const float wc0 = w_cls[dir * H_N + col];
  const float wc1 = w_cls[2 * H_N + dir * H_N + col];

  // initial h (own column) — plain load: caches fresh at dispatch boundary
  float hh = bfu2f(hx[((size_t)dir * 2 + (t0 & 1)) * 16384 + ((size_t)cg * 32 + b) * 16 + cl]);

  float* __restrict__ lslice = lpart + (size_t)wg * B_N * T_N * 2;
  unsigned int* __restrict__ myflag = flg + ((size_t)dir * 32 + cg) * 8 + w;
  const unsigned int* __restrict__ pollflag =
      flg + ((size_t)dir * 32 + (tid >> 4)) * 8 + ((tid & 15) >> 1);

  // prefetch step-0 xw gate values (plain cached loads)
  unsigned short xv[4];
  {
    const unsigned short* __restrict__ xb =
        &xw[((size_t)(dir * Tseg) * G4_N + colbase + cl) * B_N + b];
#pragma unroll
    for (int q2 = 0; q2 < 4; ++q2) xv[q2] = xb[(size_t)q2 * 512 * B_N];
  }

  const int b0 = (tid & 15) * 2, cg16 = (tid >> 4) * 16;

  for (int ts = 0; ts < Tseg; ++ts) {
    const int t = t0 + ts;

    // wait for the producer WAVE covering this thread's slice (pipelined)
    poll_flag2(pollflag, (unsigned int)t);
    // bulk-load own 64B h slice (MALL); internal vmcnt(0) drains poll straggler
    {
      uint32x4 va, vb, vc, vd;
      load64_mall(hx + ((size_t)dir * 2 + (t & 1)) * 16384 + (size_t)tid * 32,
                  va, vb, vc, vd);
      *(uint32x4*)&Ah[b0][cg16] = va;
      *(uint32x4*)&Ah[b0][cg16 + 8] = vb;
      *(uint32x4*)&Ah[b0 + 1][cg16] = vc;
      *(uint32x4*)&Ah[b0 + 1][cg16 + 8] = vd;
    }
    __syncthreads();  // S1: Ah complete (wg re-sync point)

    // previous step's logits reduce (off critical path; barrier-ordered)
    if (ts > 0 && tid < 64) {
      const int br = tid & 31, tau = tid >> 5;
      const int tp = t - 1;
      if (tp < Lb_r) {
        float s = 0.f;
#pragma unroll
        for (int k = 0; k < 16; ++k) s += lp[k][br][tau];
        const int tpos = dir ? (Lb_r - 1 - tp) : tp;
        lslice[((size_t)br * T_N + tpos) * 2 + tau] = s;
      }
    }

    // MFMA: wave w computes gate q, K-half kh partials
    {
      f32x4 acc0 = {0.f, 0.f, 0.f, 0.f}, acc1 = {0.f, 0.f, 0.f, 0.f};
      const int kb = (lane >> 4) << 3;
#pragma unroll
      for (int ks = 0; ks < 8; ++ks) {
        const int kk = kh * 256 + (ks << 5) + kb;
        short8 a0 = *(const short8*)&Ah[(lane & 15)][kk];
        short8 a1 = *(const short8*)&Ah[16 + (lane & 15)][kk];
        acc0 = __builtin_amdgcn_mfma_f32_16x16x32_bf16(a0, wfrag[ks], acc0, 0, 0, 0);
        acc1 = __builtin_amdgcn_mfma_f32_16x16x32_bf16(a1, wfrag[ks], acc1, 0, 0, 0);
      }
      const int crow = (lane >> 4) << 2;
      const int ccol = lane & 15;
#pragma unroll
      for (int j = 0; j < 4; ++j) {
        gate_p[w][crow + j][ccol] = acc0[j];
        gate_p[w][16 + crow + j][ccol] = acc1[j];
      }
    }
    __syncthreads();  // S2: gate_p ready

    // epilogue: merge K-halves, gates + state update (fp32)
    const bool valid = (t < Lb);
    float hn;
    {
      const float gi = gate_p[0][b][cl] + gate_p[1][b][cl] + bfu2f(xv[0]);
      const float gf = gate_p[2][b][cl] + gate_p[3][b][cl] + bfu2f(xv[1]);
      const float gg = gate_p[4][b][cl] + gate_p[5][b][cl] + bfu2f(xv[2]);
      const float go = gate_p[6][b][cl] + gate_p[7][b][cl] + bfu2f(xv[3]);
      const float cn = sigmf(gf) * cc + sigmf(gi) * tanhf(gg);
      hn = sigmf(go) * tanhf(cn);
      if (valid) { cc = cn; hh = hn; }
    }

    // publish h pair (MALL write-through); adjacent cols packed via shfl
    {
      const float hhp = __shfl_xor(hh, 1);
      if ((cl & 1) == 0) {
        const unsigned int pv =
            (unsigned int)f2bfu(hh) | ((unsigned int)f2bfu(hhp) << 16);
        store32_mall((unsigned int*)(hx + ((size_t)dir * 2 + ((t + 1) & 1)) * 16384 +
                                     ((size_t)cg * 32 + b) * 16 + cl),
                     pv);
      }
    }
    lp[cl][b][0] = valid ? hn * wc0 : 0.f;
    lp[cl][b][1] = valid ? hn * wc1 : 0.f;

    // per-WAVE drain + flag (no third barrier)
    asm volatile("s_waitcnt vmcnt(0)" ::: "memory");
    __builtin_amdgcn_sched_barrier(0);
    if (lane == 0)
      store32_mall(myflag, (unsigned int)(t + 1));

    // prefetch next step's xw (completes under next poll/MFMA)
    if (ts + 1 < Tseg) {
      const unsigned short* __restrict__ xb =
          &xw[((size_t)(dir * Tseg + ts + 1) * G4_N + colbase + cl) * B_N + b];
#pragma unroll
      for (int q2 = 0; q2 < 4; ++q2) xv[q2] = xb[(size_t)q2 * 512 * B_N];
    }
  }

  // final step's logits reduce
  if (tid < 64) {
    const int br = tid & 31, tau = tid >> 5;
    const int tp = t0 + Tseg - 1;
    if (tp < Lb_r) {
      float s = 0.f;
#pragma unroll
      for (int k = 0; k < 16; ++k) s += lp[k][br][tau];
      const int tpos = dir ? (Lb_r - 1 - tp) : tp;
      lslice[((size_t)br * T_N + tpos) * 2 + tau] = s;
    }
  }

  // persist c across segment launches (h persists via hx)
  c_buf[((size_t)dir * B_N + b) * H_N + col] = cc;
}

// ---------------------------------------------------------------------------
__global__ void init_kernel(ull* __restrict__ hx64, float* __restrict__ c_buf,
                            unsigned int* __restrict__ flg)
{
  const int i = blockIdx.x * 256 + threadIdx.x;  // 0..65535
  if (i < 16384) hx64[i] = 0ull;                 // hx: 128 KB of zeros
  if (i < 2 * B_N * H_N) c_buf[i] = 0.f;
  if (i < 1024) flg[i] = 0u;
}

__global__ void reduce_softmax_kernel(const float* __restrict__ lpart,
                                      const float* __restrict__ b_cls,
                                      float* __restrict__ out)
{
  const int i = blockIdx.x * 256 + threadIdx.x;  // 0..32767
  if (i >= B_N * T_N) return;
  float s0 = b_cls[0], s1 = b_cls[1];
  const float* __restrict__ p = lpart + (size_t)i * 2;
#pragma unroll 8
  for (int wg = 0; wg < 64; ++wg) {
    s0 += p[(size_t)wg * B_N * T_N * 2];
    s1 += p[(size_t)wg * B_N * T_N * 2 + 1];
  }
  const float m = fmaxf(s0, s1);
  const float e0 = expf(s0 - m), e1 = expf(s1 - m);
  const float inv = 1.f / (e0 + e1);
  out[2 * i] = e0 * inv;
  out[2 * i + 1] = e1 * inv;
}

// ---------------------------------------------------------------------------
extern "C" void kernel_launch(void* const* d_in, const int* in_sizes, int n_in,
                              void* d_out, int out_size, void* d_ws, size_t ws_size,
                              hipStream_t stream)
{
  const float* xs      = (const float*)d_in[0];
  const int*   lengths = (const int*)d_in[1];
  const float* w_ih_f  = (const float*)d_in[3];
  const float* w_hh_f  = (const float*)d_in[4];
  const float* b_f     = (const float*)d_in[5];
  const float* w_ih_b  = (const float*)d_in[6];
  const float* w_hh_b  = (const float*)d_in[7];
  const float* b_b     = (const float*)d_in[8];
  const float* w_cls   = (const float*)d_in[9];
  const float* b_cls   = (const float*)d_in[10];
  float* out = (float*)d_out;

  auto alignup = [](size_t v) { return (v + 255) & ~(size_t)255; };
  const size_t hx_b    = alignup((size_t)2 * 2 * 32 * 32 * 16 * 2);   // 128 KB
  const size_t flg_b   = alignup((size_t)1024 * 4);                   // 4 KB
  const size_t cbuf_b  = alignup((size_t)2 * B_N * H_N * 4);          // 128 KB
  const size_t lpart_b = alignup((size_t)64 * B_N * T_N * 2 * 4);     // 16 MB
  const size_t fixed = hx_b + flg_b + cbuf_b + lpart_b + 1024;

  int nseg = 1;
  while (nseg < 64) {
    const size_t xwb = alignup((size_t)2 * (T_N / nseg) * G4_N * B_N * 2);
    if (xwb + fixed <= ws_size) break;
    nseg <<= 1;
  }
  const int Tseg = T_N / nseg;
  const size_t xw_b = alignup((size_t)2 * Tseg * G4_N * B_N * 2);

  char* p = (char*)d_ws;
  unsigned short* xw = (unsigned short*)p;  p += xw_b;
  unsigned short* hx = (unsigned short*)p;  p += hx_b;
  unsigned int* flg = (unsigned int*)p;     p += flg_b;
  float* c_buf = (float*)p;                 p += cbuf_b;
  float* lpart = (float*)p;                 p += lpart_b;

  hipMemsetAsync(lpart, 0, lpart_b, stream);
  init_kernel<<<256, 256, 0, stream>>>((ull*)hx, c_buf, flg);

  for (int s = 0; s < nseg; ++s) {
    const int t0 = s * Tseg;
    dim3 g(G4_N / 64, (Tseg * B_N) / 64, 2);
    xw_gemm_kernel<<<g, 256, 0, stream>>>(xs, lengths, w_ih_f, b_f, w_ih_b, b_b, xw, t0, Tseg);
    rec_kernel<<<64, 512, 0, stream>>>(xw, w_hh_f, w_hh_b, w_cls, lengths,
                                       hx, flg, c_buf, lpart, t0, Tseg);
  }

  reduce_softmax_kernel<<<128, 256, 0, stream>>>(lpart, b_cls, out);
}